// Round 18
// baseline (81.940 us; speedup 1.0000x reference)
//
#include <hip/hip_runtime.h>
#include <hip/hip_bf16.h>
#include <math.h>

#define NB 128    // batches after reshape
#define NC 768    // channels (rows)
#define NE 64     // inner dim (cols)
#define IPG 12    // channels per conv group

typedef __hip_bfloat16 bf16;
typedef __bf16 bf16v8 __attribute__((ext_vector_type(8)));
typedef __bf16 bf16v4 __attribute__((ext_vector_type(4)));
typedef __bf16 bf16v2 __attribute__((ext_vector_type(2)));
typedef float f32x4 __attribute__((ext_vector_type(4)));
typedef unsigned int u32;
typedef u32 u32x4 __attribute__((ext_vector_type(4)));

// gelu = x * Phi(x); Phi via Abramowitz-Stegun 26.2.17 (|err| < 7.5e-8).
__device__ __forceinline__ float gelu_exact(float x) {
    float ax = fabsf(x);
    float t = __builtin_amdgcn_rcpf(fmaf(0.2316419f, ax, 1.0f));
    float poly = t * fmaf(t, fmaf(t, fmaf(t, fmaf(t, 1.330274429f,
                  -1.821255978f), 1.781477937f), -0.356563782f), 0.319381530f);
    float pdf = 0.3989422804f * __expf(-0.5f * ax * ax);
    float c = fmaf(-pdf, poly, 1.0f);
    float cdf = (x >= 0.f) ? c : 1.0f - c;
    return x * cdf;
}

#define MFMA16(a, b, c) __builtin_amdgcn_mfma_f32_16x16x32_bf16(a, b, c, 0, 0, 0)

__device__ __forceinline__ void gload_lds16(const void* g, void* l) {
    __builtin_amdgcn_global_load_lds(
        (const __attribute__((address_space(1))) void*)g,
        (__attribute__((address_space(3))) void*)l, 16, 0, 0);
}

// ---------------------------------------------------------------------------
// Kernel 1: q path (conv+res+gelu+LN, pre-scaled 0.125) + column exp-sums.
// r14 form (serial o-loop; r17's ILP restructure measured -2 us, reverted).
// ---------------------------------------------------------------------------
__global__ __launch_bounds__(256) void k_conv(
    const float* __restrict__ x, const float* __restrict__ cw,
    const float* __restrict__ cb, const float* __restrict__ lg,
    const float* __restrict__ lb, bf16* __restrict__ qo,
    float* __restrict__ sp)
{
    int b = blockIdx.x >> 4;
    int chunk = blockIdx.x & 15;
    int w = threadIdx.x >> 6;
    int g = __builtin_amdgcn_readfirstlane(chunk * 4 + w);   // wave-uniform
    int h = threadIdx.x & 63;
    const float* xb = x + ((size_t)b * NC + g * IPG) * NE;

    float xi[IPG], xm[IPG], xp[IPG];
    #pragma unroll
    for (int i = 0; i < IPG; ++i) {
        xi[i] = xb[i * NE + h];
        float up = __shfl_up(xi[i], 1);
        float dn = __shfl_down(xi[i], 1);
        xm[i] = h ? up : 0.f;
        xp[i] = (h < 63) ? dn : 0.f;
    }

    // column exp-sum partial over this block's 48 rows
    float es = 0.f;
    #pragma unroll
    for (int i = 0; i < IPG; ++i) es += __expf(xi[i]);
    __shared__ float red[4][64];
    red[w][h] = es;
    __syncthreads();
    if (w == 0) {
        float s = red[0][h] + red[1][h] + red[2][h] + red[3][h];
        sp[(size_t)(b * 16 + chunk) * 64 + h] = s;
    }

    float gam = lg[h], bet = lb[h];
    const float* wg = cw + (size_t)g * IPG * 36;

    for (int o = 0; o < IPG; ++o) {
        const float* wo = wg + o * 36;   // uniform -> s_load
        float acc = cb[g * IPG + o];
        #pragma unroll
        for (int i = 0; i < IPG; ++i)
            acc = fmaf(xm[i], wo[i*3], fmaf(xi[i], wo[i*3+1], fmaf(xp[i], wo[i*3+2], acc)));
        float gl = gelu_exact(acc + xi[o]);
        float s1 = gl, s2 = gl * gl;
        #pragma unroll
        for (int off = 32; off; off >>= 1) {
            s1 += __shfl_xor(s1, off);
            s2 += __shfl_xor(s2, off);
        }
        float mu  = s1 * (1.f / 64.f);
        float var = s2 * (1.f / 64.f) - mu * mu;
        float qn = (gl - mu) * rsqrtf(var + 1e-5f) * gam + bet;
        qo[((size_t)b * NC + g * IPG + o) * NE + h] = __float2bfloat16(qn * 0.125f);
    }
}

// ---------------------------------------------------------------------------
// Kernel 2: v = gelu(x @ fi_w^T + fi_b) via MFMA; k from the same f32 x regs.
// V stored TILED: vt2[b][kt][e][kc] -> each 32-k V tile is 4 KB contiguous.
// ---------------------------------------------------------------------------
__global__ __launch_bounds__(256) void k_vk(
    const float* __restrict__ x, const float* __restrict__ fw,
    const float* __restrict__ fb, const float* __restrict__ sp,
    bf16* __restrict__ ko, bf16* __restrict__ vt2)
{
    int chunk = blockIdx.x, b = blockIdx.y;
    int tid = threadIdx.x, w = tid >> 6, l = tid & 63;
    int lr = l & 15, lc = (l >> 4) * 8;
    int rowb = chunk * 64 + w * 16;
    const float* xb = x + (size_t)b * NC * NE;

    __shared__ float sts[64];
    if (tid < 64) {
        float s = 0.f;
        #pragma unroll
        for (int p = 0; p < 16; ++p) s += sp[(size_t)(b * 16 + p) * 64 + tid];
        sts[tid] = 1.f / s;
    }

    bf16v8 bfr[4][2];
    float fbias[4];
    #pragma unroll
    for (int nt = 0; nt < 4; ++nt) {
        #pragma unroll
        for (int kt = 0; kt < 2; ++kt) {
            const float* p = fw + (nt*16 + lr) * 64 + kt*32 + lc;
            bf16v8 t;
            #pragma unroll
            for (int j = 0; j < 8; ++j) t[j] = (__bf16)p[j];
            bfr[nt][kt] = t;
        }
        fbias[nt] = fb[nt*16 + lr];
    }
    __syncthreads();

    float isA[8], isB[8];
    #pragma unroll
    for (int j = 0; j < 8; ++j) { isA[j] = sts[lc + j]; isB[j] = sts[32 + lc + j]; }

    const float* pa = xb + (size_t)(rowb + lr) * NE;
    float xa[8], xc[8];
    #pragma unroll
    for (int j = 0; j < 8; ++j) xa[j] = pa[lc + j];
    #pragma unroll
    for (int j = 0; j < 8; ++j) xc[j] = pa[32 + lc + j];

    bf16v8 a0, a1;
    #pragma unroll
    for (int j = 0; j < 8; ++j) a0[j] = (__bf16)xa[j];
    #pragma unroll
    for (int j = 0; j < 8; ++j) a1[j] = (__bf16)xc[j];

    // ---- k path from registers ----
    bf16v8 kv0, kv1;
    #pragma unroll
    for (int j = 0; j < 8; ++j) kv0[j] = (__bf16)gelu_exact(__expf(xa[j]) * isA[j]);
    #pragma unroll
    for (int j = 0; j < 8; ++j) kv1[j] = (__bf16)gelu_exact(__expf(xc[j]) * isB[j]);
    bf16* kp = ko + ((size_t)b * NC + rowb + lr) * NE + lc;
    *(bf16v8*)kp = kv0;
    *(bf16v8*)(kp + 32) = kv1;

    // ---- v MFMAs -> tiled store ----
    int c0 = rowb + (l >> 4) * 4;          // 4 consecutive k-rows, same tile
    int ktile = c0 >> 5, kc = c0 & 31;
    #pragma unroll
    for (int nt = 0; nt < 4; ++nt) {
        f32x4 acc = {fbias[nt], fbias[nt], fbias[nt], fbias[nt]};
        acc = MFMA16(a0, bfr[nt][0], acc);
        acc = MFMA16(a1, bfr[nt][1], acc);
        bf16v4 pk;
        #pragma unroll
        for (int r = 0; r < 4; ++r) pk[r] = (__bf16)gelu_exact(acc[r]);
        *(bf16v4*)&vt2[(((size_t)b * 24 + ktile) * 64 + nt*16 + lr) * 32 + kc] = pk;
    }
}

// ---------------------------------------------------------------------------
// softmax + P-redistribution for one 16-q tile (verified mapping, rounds 3-14):
// lane holds S[k-frag rows][q=lr]; returns PV A-frag P[q=lr][k chunk hi*8..+7].
// __expf on pre-scaled (0.125) scores — the FAST ocml path (r13 lesson).
// ---------------------------------------------------------------------------
__device__ __forceinline__ bf16v8 softmax_exch(f32x4 s0, f32x4 s1, float& rsum,
                                               int srcA, int srcB, int hq) {
    float p0 = __expf(s0[0]), p1 = __expf(s0[1]), p2 = __expf(s0[2]), p3 = __expf(s0[3]);
    float p4 = __expf(s1[0]), p5 = __expf(s1[1]), p6 = __expf(s1[2]), p7 = __expf(s1[3]);
    rsum += ((p0 + p1) + (p2 + p3)) + ((p4 + p5) + (p6 + p7));
    bf16v2 t0; t0[0] = (__bf16)p0; t0[1] = (__bf16)p1;
    bf16v2 t1; t1[0] = (__bf16)p2; t1[1] = (__bf16)p3;
    bf16v2 t2; t2[0] = (__bf16)p4; t2[1] = (__bf16)p5;
    bf16v2 t3; t3[0] = (__bf16)p6; t3[1] = (__bf16)p7;
    u32 w0 = __builtin_bit_cast(u32, t0), w1 = __builtin_bit_cast(u32, t1);
    u32 w2 = __builtin_bit_cast(u32, t2), w3 = __builtin_bit_cast(u32, t3);
    u32 c0A = (u32)__shfl((int)w0, srcA), c1A = (u32)__shfl((int)w1, srcA);
    u32 c2A = (u32)__shfl((int)w2, srcA), c3A = (u32)__shfl((int)w3, srcA);
    u32 c0B = (u32)__shfl((int)w0, srcB), c1B = (u32)__shfl((int)w1, srcB);
    u32 c2B = (u32)__shfl((int)w2, srcB), c3B = (u32)__shfl((int)w3, srcB);
    u32x4 pau = { hq ? c2A : c0A, hq ? c3A : c1A,
                  hq ? c2B : c0B, hq ? c3B : c1B };
    return __builtin_bit_cast(bf16v8, pau);
}

// ---------------------------------------------------------------------------
// Kernel 3: attention — TLP variant. 16 q-rows/wave (64/block), BK=32,
// LDS 16 KB, grid 1536 (= 8 XCD * 192) -> 6 blocks/CU, 24 waves/CU (was 12).
// All scheduling variants at 12 waves/CU were null (rounds 10-12); this
// attacks the latency-bound phase with independent-block overlap instead.
// Staging + swizzle formulas carried verbatim from r14 (per 32-row tile).
// ---------------------------------------------------------------------------
__global__ __launch_bounds__(256, 6) void k_attn(const bf16* __restrict__ qb,
                                                 const bf16* __restrict__ kb,
                                                 const bf16* __restrict__ vt2,
                                                 float* __restrict__ out) {
    __shared__ __align__(16) __bf16 ldsK[2][2048];   // [buf][32 r][64 e] swz
    __shared__ __align__(16) __bf16 ldsV[2][2048];   // [buf][64 e][32 k] swz

    int bid = blockIdx.x;
    int swz = (bid & 7) * 192 + (bid >> 3);     // bijective: 1536 = 8*192
    int b = swz / 12, qt = swz - b * 12;
    int w = threadIdx.x >> 6, l = threadIdx.x & 63;
    int q0 = qt * 64 + w * 16;
    int lr = l & 15, hi = l >> 4;
    int hq = hi >> 1;
    int srcA = lr + ((hi & 1) << 5);
    int srcB = srcA + 16;

    // staging source addresses (inverse-swizzled, r14 formulas)
    int krow_ = w * 8 + (l >> 3);
    int kc16_ = (l & 7) ^ (l >> 3);
    const char* kgbase = (const char*)(kb + (size_t)b * NC * NE)
                       + krow_ * 128 + kc16_ * 16;
    int ve_   = w * 16 + (l >> 2);
    int vc16_ = (l & 3) ^ ((l >> 3) & 3);
    const char* vgbase = (const char*)vt2 + (size_t)b * 24 * 4096
                       + ve_ * 64 + vc16_ * 16;

    // swizzled ds_read element offsets (within one 2048-elem tile)
    int krd0 = lr * 64 + ((hi ^ (lr & 7)) << 3);
    int krd1 = lr * 64 + (((4 + hi) ^ (lr & 7)) << 3);
    int vsel = (lr >> 1) & 3;
    int vrd  = lr * 32 + ((hi ^ vsel) << 3);

    const bf16* qp = qb + ((size_t)b * NC + q0 + lr) * NE + hi * 8;
    bf16v8 qf0 = *(const bf16v8*)qp;
    bf16v8 qf1 = *(const bf16v8*)(qp + 32);

    f32x4 o0 = {0,0,0,0}, o1 = {0,0,0,0}, o2 = {0,0,0,0}, o3 = {0,0,0,0};
    float rsum = 0.f;

    // prologue: stage k-tile 0 into buf 0
    gload_lds16(kgbase, &ldsK[0][w * 512]);
    gload_lds16(vgbase, &ldsV[0][w * 512]);
    __syncthreads();

    int cur = 0;
    for (int t = 0; t < 24; ++t) {
        if (t < 23) {   // stage tile t+1 into the other buffer (issue early)
            gload_lds16(kgbase + (size_t)(t + 1) * 4096, &ldsK[cur ^ 1][w * 512]);
            gload_lds16(vgbase + (size_t)(t + 1) * 4096, &ldsV[cur ^ 1][w * 512]);
        }

        const __bf16* Kc = ldsK[cur];
        const __bf16* Vc = ldsV[cur];
        bf16v8 ka0 = *(const bf16v8*)&Kc[krd0];
        bf16v8 ka1 = *(const bf16v8*)&Kc[krd1];
        bf16v8 ka2 = *(const bf16v8*)&Kc[krd0 + 1024];
        bf16v8 ka3 = *(const bf16v8*)&Kc[krd1 + 1024];
        bf16v8 v0  = *(const bf16v8*)&Vc[vrd];
        bf16v8 v1  = *(const bf16v8*)&Vc[vrd + 512];
        bf16v8 v2  = *(const bf16v8*)&Vc[vrd + 1024];
        bf16v8 v3  = *(const bf16v8*)&Vc[vrd + 1536];

        __builtin_amdgcn_s_setprio(1);
        f32x4 s0 = {0,0,0,0}, s1 = {0,0,0,0};
        s0 = MFMA16(ka0, qf0, s0);
        s0 = MFMA16(ka1, qf1, s0);
        s1 = MFMA16(ka2, qf0, s1);
        s1 = MFMA16(ka3, qf1, s1);
        __builtin_amdgcn_s_setprio(0);

        bf16v8 pa = softmax_exch(s0, s1, rsum, srcA, srcB, hq);

        __builtin_amdgcn_s_setprio(1);
        o0 = MFMA16(pa, v0, o0);
        o1 = MFMA16(pa, v1, o1);
        o2 = MFMA16(pa, v2, o2);
        o3 = MFMA16(pa, v3, o3);
        __builtin_amdgcn_s_setprio(0);

        __syncthreads();   // drains staging vmcnt; flips buffers safely
        cur ^= 1;
    }

    rsum += __shfl_xor(rsum, 16);
    rsum += __shfl_xor(rsum, 32);
    float inv = 1.f / rsum;

    int qrow = q0 + hi * 4;
    #pragma unroll
    for (int r = 0; r < 4; ++r) {
        float iq = __shfl(inv, hi * 4 + r);
        float* op = out + ((size_t)b * NC + qrow + r) * NE + lr;
        op[0]  = o0[r] * iq;
        op[16] = o1[r] * iq;
        op[32] = o2[r] * iq;
        op[48] = o3[r] * iq;
    }
}

// ---------------------------------------------------------------------------
extern "C" void kernel_launch(void* const* d_in, const int* in_sizes, int n_in,
                              void* d_out, int out_size, void* d_ws, size_t ws_size,
                              hipStream_t stream) {
    (void)in_sizes; (void)n_in; (void)out_size; (void)ws_size;
    const float* x      = (const float*)d_in[0];
    const float* conv_w = (const float*)d_in[1];
    const float* conv_b = (const float*)d_in[2];
    const float* ln_g   = (const float*)d_in[3];
    const float* ln_b   = (const float*)d_in[4];
    const float* fi_w   = (const float*)d_in[5];
    const float* fi_b   = (const float*)d_in[6];
    // bi_w/bi_b unused: mask is constant along softmax axis -> exact no-op.

    bf16* qbuf = (bf16*)d_ws;
    bf16* kbuf = qbuf + (size_t)NB * NC * NE;
    bf16* vt2  = kbuf + (size_t)NB * NC * NE;             // tiled V
    float* stats = (float*)(vt2 + (size_t)NB * NC * NE);  // NB*16*64 f32
    float* out = (float*)d_out;

    k_conv<<<dim3(NB * 16), 256, 0, stream>>>(x, conv_w, conv_b, ln_g, ln_b,
                                              qbuf, stats);
    k_vk<<<dim3(12, NB), 256, 0, stream>>>(x, fi_w, fi_b, stats, kbuf, vt2);
    k_attn<<<dim3(768 * 2), 256, 0, stream>>>(qbuf, kbuf, vt2, out);
}

// Round 19
// 79.290 us; speedup vs baseline: 1.0334x; 1.0334x over previous
//
#include <hip/hip_runtime.h>
#include <hip/hip_bf16.h>
#include <math.h>

#define NB 128    // batches after reshape
#define NC 768    // channels (rows)
#define NE 64     // inner dim (cols)
#define IPG 12    // channels per conv group

typedef __hip_bfloat16 bf16;
typedef __bf16 bf16v8 __attribute__((ext_vector_type(8)));
typedef __bf16 bf16v4 __attribute__((ext_vector_type(4)));
typedef __bf16 bf16v2 __attribute__((ext_vector_type(2)));
typedef float f32x4 __attribute__((ext_vector_type(4)));
typedef unsigned int u32;
typedef u32 u32x4 __attribute__((ext_vector_type(4)));

// gelu = x * Phi(x); Phi via Abramowitz-Stegun 26.2.17 (|err| < 7.5e-8).
__device__ __forceinline__ float gelu_exact(float x) {
    float ax = fabsf(x);
    float t = __builtin_amdgcn_rcpf(fmaf(0.2316419f, ax, 1.0f));
    float poly = t * fmaf(t, fmaf(t, fmaf(t, fmaf(t, 1.330274429f,
                  -1.821255978f), 1.781477937f), -0.356563782f), 0.319381530f);
    float pdf = 0.3989422804f * __expf(-0.5f * ax * ax);
    float c = fmaf(-pdf, poly, 1.0f);
    float cdf = (x >= 0.f) ? c : 1.0f - c;
    return x * cdf;
}

#define MFMA16(a, b, c) __builtin_amdgcn_mfma_f32_16x16x32_bf16(a, b, c, 0, 0, 0)

__device__ __forceinline__ void gload_lds16(const void* g, void* l) {
    __builtin_amdgcn_global_load_lds(
        (const __attribute__((address_space(1))) void*)g,
        (__attribute__((address_space(3))) void*)l, 16, 0, 0);
}

// ---------------------------------------------------------------------------
// Kernel 1: MERGED producer, block-type specialized (conv-blocks || v-blocks
// co-resident in one dispatch — overlaps conv's shuffle-latency stalls with
// v's MFMA/memory work; r15's intra-block serial fusion regressed, this is
// inter-BLOCK concurrency instead).
//   blocks [0, 2048):  conv+gelu+LN -> q (prescaled 0.125) + stats partials
//   blocks [2048, 3584): v = gelu(x @ fi_w^T + fi_b) -> tiled vt2 (no stats)
// ---------------------------------------------------------------------------
__global__ __launch_bounds__(256) void k_prod2(
    const float* __restrict__ x, const float* __restrict__ cw,
    const float* __restrict__ cb, const float* __restrict__ lg,
    const float* __restrict__ lb, const float* __restrict__ fw,
    const float* __restrict__ fb, bf16* __restrict__ qo,
    float* __restrict__ sp, bf16* __restrict__ vt2)
{
    __shared__ float red[4][64];
    int bid = blockIdx.x;
    int tid = threadIdx.x, w = tid >> 6, l = tid & 63;

    if (bid < 2048) {
        // ================= conv/q path (r14 k_conv, verbatim) =============
        int b = bid >> 4;
        int chunk = bid & 15;
        int g = __builtin_amdgcn_readfirstlane(chunk * 4 + w);   // uniform
        int h = l;
        const float* xb = x + ((size_t)b * NC + g * IPG) * NE;

        float xi[IPG], xm[IPG], xp[IPG];
        #pragma unroll
        for (int i = 0; i < IPG; ++i) {
            xi[i] = xb[i * NE + h];
            float up = __shfl_up(xi[i], 1);
            float dn = __shfl_down(xi[i], 1);
            xm[i] = h ? up : 0.f;
            xp[i] = (h < 63) ? dn : 0.f;
        }

        float es = 0.f;
        #pragma unroll
        for (int i = 0; i < IPG; ++i) es += __expf(xi[i]);
        red[w][h] = es;
        __syncthreads();
        if (w == 0) {
            float s = red[0][h] + red[1][h] + red[2][h] + red[3][h];
            sp[(size_t)(b * 16 + chunk) * 64 + h] = s;
        }

        float gam = lg[h], bet = lb[h];
        const float* wg = cw + (size_t)g * IPG * 36;

        for (int o = 0; o < IPG; ++o) {
            const float* wo = wg + o * 36;   // uniform -> s_load
            float acc = cb[g * IPG + o];
            #pragma unroll
            for (int i = 0; i < IPG; ++i)
                acc = fmaf(xm[i], wo[i*3], fmaf(xi[i], wo[i*3+1], fmaf(xp[i], wo[i*3+2], acc)));
            float gl = gelu_exact(acc + xi[o]);
            float s1 = gl, s2 = gl * gl;
            #pragma unroll
            for (int off = 32; off; off >>= 1) {
                s1 += __shfl_xor(s1, off);
                s2 += __shfl_xor(s2, off);
            }
            float mu  = s1 * (1.f / 64.f);
            float var = s2 * (1.f / 64.f) - mu * mu;
            float qn = (gl - mu) * rsqrtf(var + 1e-5f) * gam + bet;
            qo[((size_t)b * NC + g * IPG + o) * NE + h] = __float2bfloat16(qn * 0.125f);
        }
    } else {
        // ================= v path (r14 k_vk minus k/stats) ================
        int vid = bid - 2048;               // 0..1535
        int chunk = vid % 12;
        int b = vid / 12;
        int lr = l & 15, lc = (l >> 4) * 8;
        int rowb = chunk * 64 + w * 16;
        const float* xb = x + (size_t)b * NC * NE;

        bf16v8 bfr[4][2];
        float fbias[4];
        #pragma unroll
        for (int nt = 0; nt < 4; ++nt) {
            #pragma unroll
            for (int kt = 0; kt < 2; ++kt) {
                const float* p = fw + (nt*16 + lr) * 64 + kt*32 + lc;
                bf16v8 t;
                #pragma unroll
                for (int j = 0; j < 8; ++j) t[j] = (__bf16)p[j];
                bfr[nt][kt] = t;
            }
            fbias[nt] = fb[nt*16 + lr];
        }

        const float* pa = xb + (size_t)(rowb + lr) * NE;
        bf16v8 a0, a1;
        #pragma unroll
        for (int j = 0; j < 8; ++j) a0[j] = (__bf16)pa[lc + j];
        #pragma unroll
        for (int j = 0; j < 8; ++j) a1[j] = (__bf16)pa[32 + lc + j];

        int c0 = rowb + (l >> 4) * 4;       // 4 consecutive k-rows, same tile
        int ktile = c0 >> 5, kc = c0 & 31;
        #pragma unroll
        for (int nt = 0; nt < 4; ++nt) {
            f32x4 acc = {fbias[nt], fbias[nt], fbias[nt], fbias[nt]};
            acc = MFMA16(a0, bfr[nt][0], acc);
            acc = MFMA16(a1, bfr[nt][1], acc);
            bf16v4 pk;
            #pragma unroll
            for (int r = 0; r < 4; ++r) pk[r] = (__bf16)gelu_exact(acc[r]);
            *(bf16v4*)&vt2[(((size_t)b * 24 + ktile) * 64 + nt*16 + lr) * 32 + kc] = pk;
        }
    }
}

// ---------------------------------------------------------------------------
// Kernel 2: k-build — k = gelu(exp(x) * inv_colsum), elementwise; x is fully
// L3-resident (25 MB). Grid (12, NB): 64 rows per block, 16 elems/thread.
// ---------------------------------------------------------------------------
__global__ __launch_bounds__(256) void k_kbuild(
    const float* __restrict__ x, const float* __restrict__ sp,
    bf16* __restrict__ ko)
{
    int chunk = blockIdx.x, b = blockIdx.y;
    int tid = threadIdx.x, w = tid >> 6, l = tid & 63;
    int lr = l & 15, lc = (l >> 4) * 8;
    int rowb = chunk * 64 + w * 16;

    __shared__ float sts[64];
    if (tid < 64) {
        float s = 0.f;
        #pragma unroll
        for (int p = 0; p < 16; ++p) s += sp[(size_t)(b * 16 + p) * 64 + tid];
        sts[tid] = 1.f / s;
    }
    __syncthreads();

    float isA[8], isB[8];
    #pragma unroll
    for (int j = 0; j < 8; ++j) { isA[j] = sts[lc + j]; isB[j] = sts[32 + lc + j]; }

    const float* pa = x + ((size_t)b * NC + rowb + lr) * NE;
    bf16v8 kv0, kv1;
    #pragma unroll
    for (int j = 0; j < 8; ++j) kv0[j] = (__bf16)gelu_exact(__expf(pa[lc + j]) * isA[j]);
    #pragma unroll
    for (int j = 0; j < 8; ++j) kv1[j] = (__bf16)gelu_exact(__expf(pa[32 + lc + j]) * isB[j]);
    bf16* kp = ko + ((size_t)b * NC + rowb + lr) * NE + lc;
    *(bf16v8*)kp = kv0;
    *(bf16v8*)(kp + 32) = kv1;
}

// ---------------------------------------------------------------------------
// softmax + P-redistribution for one 16-q tile (verified mapping, rounds 3-18):
// lane holds S[k-frag rows][q=lr]; returns PV A-frag P[q=lr][k chunk hi*8..+7].
// __expf on pre-scaled (0.125) scores — the FAST ocml path (r13 lesson).
// ---------------------------------------------------------------------------
__device__ __forceinline__ bf16v8 softmax_exch(f32x4 s0, f32x4 s1, float& rsum,
                                               int srcA, int srcB, int hq) {
    float p0 = __expf(s0[0]), p1 = __expf(s0[1]), p2 = __expf(s0[2]), p3 = __expf(s0[3]);
    float p4 = __expf(s1[0]), p5 = __expf(s1[1]), p6 = __expf(s1[2]), p7 = __expf(s1[3]);
    rsum += ((p0 + p1) + (p2 + p3)) + ((p4 + p5) + (p6 + p7));
    bf16v2 t0; t0[0] = (__bf16)p0; t0[1] = (__bf16)p1;
    bf16v2 t1; t1[0] = (__bf16)p2; t1[1] = (__bf16)p3;
    bf16v2 t2; t2[0] = (__bf16)p4; t2[1] = (__bf16)p5;
    bf16v2 t3; t3[0] = (__bf16)p6; t3[1] = (__bf16)p7;
    u32 w0 = __builtin_bit_cast(u32, t0), w1 = __builtin_bit_cast(u32, t1);
    u32 w2 = __builtin_bit_cast(u32, t2), w3 = __builtin_bit_cast(u32, t3);
    u32 c0A = (u32)__shfl((int)w0, srcA), c1A = (u32)__shfl((int)w1, srcA);
    u32 c2A = (u32)__shfl((int)w2, srcA), c3A = (u32)__shfl((int)w3, srcA);
    u32 c0B = (u32)__shfl((int)w0, srcB), c1B = (u32)__shfl((int)w1, srcB);
    u32 c2B = (u32)__shfl((int)w2, srcB), c3B = (u32)__shfl((int)w3, srcB);
    u32x4 pau = { hq ? c2A : c0A, hq ? c3A : c1A,
                  hq ? c2B : c0B, hq ? c3B : c1B };
    return __builtin_bit_cast(bf16v8, pau);
}

// ---------------------------------------------------------------------------
// Kernel 3: attention — byte-identical to round 14 (best measured: 40.7 us;
// invariant to occupancy/pipeline/tile variants per rounds 10-18, treated as
// session floor). 16x16 body, __expf, tiled-V staging, 2-buf BK=64, setprio,
// verified swizzles. Grid 768 = 8 XCD * 96; LDS 32 KB; 3 blocks/CU.
// ---------------------------------------------------------------------------
__global__ __launch_bounds__(256, 3) void k_attn(const bf16* __restrict__ qb,
                                                 const bf16* __restrict__ kb,
                                                 const bf16* __restrict__ vt2,
                                                 float* __restrict__ out) {
    __shared__ __align__(16) __bf16 ldsK[2][4096];   // [buf][2 sub][32 r][64 e]
    __shared__ __align__(16) __bf16 ldsV[2][4096];   // [buf][2 sub][64 e][32 k]

    int bid = blockIdx.x;
    int swz = (bid & 7) * 96 + (bid >> 3);      // bijective: 768 = 8*96
    int b = swz / 6, qt = swz - b * 6;
    int w = threadIdx.x >> 6, l = threadIdx.x & 63;
    int q0 = qt * 128 + w * 32;
    int lr = l & 15, hi = l >> 4;
    int hq = hi >> 1;
    int srcA = lr + ((hi & 1) << 5);
    int srcB = srcA + 16;

    int krow_ = w * 8 + (l >> 3);
    int kc16_ = (l & 7) ^ (l >> 3);
    const char* kgbase = (const char*)(kb + (size_t)b * NC * NE)
                       + krow_ * 128 + kc16_ * 16;
    int ve_   = w * 16 + (l >> 2);
    int vc16_ = (l & 3) ^ ((l >> 3) & 3);
    const char* vgbase = (const char*)vt2 + (size_t)b * 24 * 4096
                       + ve_ * 64 + vc16_ * 16;

    int krd0 = lr * 64 + ((hi ^ (lr & 7)) << 3);
    int krd1 = lr * 64 + (((4 + hi) ^ (lr & 7)) << 3);
    int vsel = (lr >> 1) & 3;
    int vrd  = lr * 32 + ((hi ^ vsel) << 3);

    const bf16* qp = qb + ((size_t)b * NC + q0 + lr) * NE + hi * 8;
    bf16v8 qf00 = *(const bf16v8*)qp;
    bf16v8 qf01 = *(const bf16v8*)(qp + 32);
    bf16v8 qf10 = *(const bf16v8*)(qp + 16 * NE);
    bf16v8 qf11 = *(const bf16v8*)(qp + 16 * NE + 32);

    f32x4 o00 = {0,0,0,0}, o01 = {0,0,0,0}, o02 = {0,0,0,0}, o03 = {0,0,0,0};
    f32x4 o10 = {0,0,0,0}, o11 = {0,0,0,0}, o12 = {0,0,0,0}, o13 = {0,0,0,0};
    float rsum0 = 0.f, rsum1 = 0.f;

    gload_lds16(kgbase,        &ldsK[0][w * 512]);
    gload_lds16(kgbase + 4096, &ldsK[0][2048 + w * 512]);
    gload_lds16(vgbase,        &ldsV[0][w * 512]);
    gload_lds16(vgbase + 4096, &ldsV[0][2048 + w * 512]);
    __syncthreads();

    int cur = 0;
    for (int ph = 0; ph < 12; ++ph) {
        if (ph < 11) {
            const char* kg = kgbase + (size_t)(2 * ph + 2) * 4096;
            gload_lds16(kg,        &ldsK[cur ^ 1][w * 512]);
            gload_lds16(kg + 4096, &ldsK[cur ^ 1][2048 + w * 512]);
            const char* vg = vgbase + (size_t)(2 * ph + 2) * 4096;
            gload_lds16(vg,        &ldsV[cur ^ 1][w * 512]);
            gload_lds16(vg + 4096, &ldsV[cur ^ 1][2048 + w * 512]);
        }

        #pragma unroll
        for (int sub = 0; sub < 2; ++sub) {
            const __bf16* Kc = &ldsK[cur][sub * 2048];
            const __bf16* Vc = &ldsV[cur][sub * 2048];
            bf16v8 ka0 = *(const bf16v8*)&Kc[krd0];
            bf16v8 ka1 = *(const bf16v8*)&Kc[krd1];
            bf16v8 ka2 = *(const bf16v8*)&Kc[krd0 + 1024];
            bf16v8 ka3 = *(const bf16v8*)&Kc[krd1 + 1024];
            bf16v8 v0  = *(const bf16v8*)&Vc[vrd];
            bf16v8 v1  = *(const bf16v8*)&Vc[vrd + 512];
            bf16v8 v2  = *(const bf16v8*)&Vc[vrd + 1024];
            bf16v8 v3  = *(const bf16v8*)&Vc[vrd + 1536];

            __builtin_amdgcn_s_setprio(1);
            f32x4 s00 = {0,0,0,0}, s01 = {0,0,0,0};
            s00 = MFMA16(ka0, qf00, s00);
            s00 = MFMA16(ka1, qf01, s00);
            s01 = MFMA16(ka2, qf00, s01);
            s01 = MFMA16(ka3, qf01, s01);
            f32x4 s10 = {0,0,0,0}, s11 = {0,0,0,0};
            s10 = MFMA16(ka0, qf10, s10);
            s10 = MFMA16(ka1, qf11, s10);
            s11 = MFMA16(ka2, qf10, s11);
            s11 = MFMA16(ka3, qf11, s11);
            __builtin_amdgcn_s_setprio(0);

            bf16v8 pa0 = softmax_exch(s00, s01, rsum0, srcA, srcB, hq);
            bf16v8 pa1 = softmax_exch(s10, s11, rsum1, srcA, srcB, hq);

            __builtin_amdgcn_s_setprio(1);
            o00 = MFMA16(pa0, v0, o00);
            o01 = MFMA16(pa0, v1, o01);
            o02 = MFMA16(pa0, v2, o02);
            o03 = MFMA16(pa0, v3, o03);
            o10 = MFMA16(pa1, v0, o10);
            o11 = MFMA16(pa1, v1, o11);
            o12 = MFMA16(pa1, v2, o12);
            o13 = MFMA16(pa1, v3, o13);
            __builtin_amdgcn_s_setprio(0);
        }

        __syncthreads();
        cur ^= 1;
    }

    rsum0 += __shfl_xor(rsum0, 16);
    rsum0 += __shfl_xor(rsum0, 32);
    rsum1 += __shfl_xor(rsum1, 16);
    rsum1 += __shfl_xor(rsum1, 32);
    float inv0 = 1.f / rsum0, inv1 = 1.f / rsum1;

    int qrow0 = q0 + hi * 4;
    #pragma unroll
    for (int r = 0; r < 4; ++r) {
        float iq = __shfl(inv0, hi * 4 + r);
        float* op = out + ((size_t)b * NC + qrow0 + r) * NE + lr;
        op[0]  = o00[r] * iq;
        op[16] = o01[r] * iq;
        op[32] = o02[r] * iq;
        op[48] = o03[r] * iq;
    }
    int qrow1 = q0 + 16 + hi * 4;
    #pragma unroll
    for (int r = 0; r < 4; ++r) {
        float iq = __shfl(inv1, hi * 4 + r);
        float* op = out + ((size_t)b * NC + qrow1 + r) * NE + lr;
        op[0]  = o10[r] * iq;
        op[16] = o11[r] * iq;
        op[32] = o12[r] * iq;
        op[48] = o13[r] * iq;
    }
}

// ---------------------------------------------------------------------------
extern "C" void kernel_launch(void* const* d_in, const int* in_sizes, int n_in,
                              void* d_out, int out_size, void* d_ws, size_t ws_size,
                              hipStream_t stream) {
    (void)in_sizes; (void)n_in; (void)out_size; (void)ws_size;
    const float* x      = (const float*)d_in[0];
    const float* conv_w = (const float*)d_in[1];
    const float* conv_b = (const float*)d_in[2];
    const float* ln_g   = (const float*)d_in[3];
    const float* ln_b   = (const float*)d_in[4];
    const float* fi_w   = (const float*)d_in[5];
    const float* fi_b   = (const float*)d_in[6];
    // bi_w/bi_b unused: mask is constant along softmax axis -> exact no-op.

    bf16* qbuf = (bf16*)d_ws;
    bf16* kbuf = qbuf + (size_t)NB * NC * NE;
    bf16* vt2  = kbuf + (size_t)NB * NC * NE;             // tiled V
    float* stats = (float*)(vt2 + (size_t)NB * NC * NE);  // NB*16*64 f32
    float* out = (float*)d_out;

    k_prod2<<<dim3(2048 + 1536), 256, 0, stream>>>(x, conv_w, conv_b, ln_g,
                                                   ln_b, fi_w, fi_b, qbuf,
                                                   stats, vt2);
    k_kbuild<<<dim3(12, NB), 256, 0, stream>>>(x, stats, kbuf);
    k_attn<<<dim3(768), 256, 0, stream>>>(qbuf, kbuf, vt2, out);
}

// Round 20
// 78.343 us; speedup vs baseline: 1.0459x; 1.0121x over previous
//
#include <hip/hip_runtime.h>
#include <hip/hip_bf16.h>
#include <math.h>

#define NB 128    // batches after reshape
#define NC 768    // channels (rows)
#define NE 64     // inner dim (cols)
#define IPG 12    // channels per conv group

typedef __hip_bfloat16 bf16;
typedef __bf16 bf16v8 __attribute__((ext_vector_type(8)));
typedef __bf16 bf16v4 __attribute__((ext_vector_type(4)));
typedef __bf16 bf16v2 __attribute__((ext_vector_type(2)));
typedef float f32x4 __attribute__((ext_vector_type(4)));
typedef unsigned int u32;
typedef u32 u32x4 __attribute__((ext_vector_type(4)));

// gelu = x * Phi(x); Phi via Abramowitz-Stegun 26.2.17 (|err| < 7.5e-8).
__device__ __forceinline__ float gelu_exact(float x) {
    float ax = fabsf(x);
    float t = __builtin_amdgcn_rcpf(fmaf(0.2316419f, ax, 1.0f));
    float poly = t * fmaf(t, fmaf(t, fmaf(t, fmaf(t, 1.330274429f,
                  -1.821255978f), 1.781477937f), -0.356563782f), 0.319381530f);
    float pdf = 0.3989422804f * __expf(-0.5f * ax * ax);
    float c = fmaf(-pdf, poly, 1.0f);
    float cdf = (x >= 0.f) ? c : 1.0f - c;
    return x * cdf;
}

#define MFMA16(a, b, c) __builtin_amdgcn_mfma_f32_16x16x32_bf16(a, b, c, 0, 0, 0)

__device__ __forceinline__ void gload_lds16(const void* g, void* l) {
    __builtin_amdgcn_global_load_lds(
        (const __attribute__((address_space(1))) void*)g,
        (__attribute__((address_space(3))) void*)l, 16, 0, 0);
}

// ---------------------------------------------------------------------------
// Kernel 1: q path (conv+res+gelu+LN, pre-scaled 0.125) + column exp-sums.
// r14 configuration — measured session best (78.2 us total).
// ---------------------------------------------------------------------------
__global__ __launch_bounds__(256) void k_conv(
    const float* __restrict__ x, const float* __restrict__ cw,
    const float* __restrict__ cb, const float* __restrict__ lg,
    const float* __restrict__ lb, bf16* __restrict__ qo,
    float* __restrict__ sp)
{
    int b = blockIdx.x >> 4;
    int chunk = blockIdx.x & 15;
    int w = threadIdx.x >> 6;
    int g = __builtin_amdgcn_readfirstlane(chunk * 4 + w);   // wave-uniform
    int h = threadIdx.x & 63;
    const float* xb = x + ((size_t)b * NC + g * IPG) * NE;

    float xi[IPG], xm[IPG], xp[IPG];
    #pragma unroll
    for (int i = 0; i < IPG; ++i) {
        xi[i] = xb[i * NE + h];
        float up = __shfl_up(xi[i], 1);
        float dn = __shfl_down(xi[i], 1);
        xm[i] = h ? up : 0.f;
        xp[i] = (h < 63) ? dn : 0.f;
    }

    // column exp-sum partial over this block's 48 rows
    float es = 0.f;
    #pragma unroll
    for (int i = 0; i < IPG; ++i) es += __expf(xi[i]);
    __shared__ float red[4][64];
    red[w][h] = es;
    __syncthreads();
    if (w == 0) {
        float s = red[0][h] + red[1][h] + red[2][h] + red[3][h];
        sp[(size_t)(b * 16 + chunk) * 64 + h] = s;
    }

    float gam = lg[h], bet = lb[h];
    const float* wg = cw + (size_t)g * IPG * 36;

    for (int o = 0; o < IPG; ++o) {
        const float* wo = wg + o * 36;   // uniform -> s_load
        float acc = cb[g * IPG + o];
        #pragma unroll
        for (int i = 0; i < IPG; ++i)
            acc = fmaf(xm[i], wo[i*3], fmaf(xi[i], wo[i*3+1], fmaf(xp[i], wo[i*3+2], acc)));
        float gl = gelu_exact(acc + xi[o]);
        float s1 = gl, s2 = gl * gl;
        #pragma unroll
        for (int off = 32; off; off >>= 1) {
            s1 += __shfl_xor(s1, off);
            s2 += __shfl_xor(s2, off);
        }
        float mu  = s1 * (1.f / 64.f);
        float var = s2 * (1.f / 64.f) - mu * mu;
        float qn = (gl - mu) * rsqrtf(var + 1e-5f) * gam + bet;
        qo[((size_t)b * NC + g * IPG + o) * NE + h] = __float2bfloat16(qn * 0.125f);
    }
}

// ---------------------------------------------------------------------------
// Kernel 2: v = gelu(x @ fi_w^T + fi_b) via MFMA; k from the same f32 x regs.
// V stored TILED: vt2[b][kt][e][kc] -> each 32-k V tile is 4 KB contiguous.
// ---------------------------------------------------------------------------
__global__ __launch_bounds__(256) void k_vk(
    const float* __restrict__ x, const float* __restrict__ fw,
    const float* __restrict__ fb, const float* __restrict__ sp,
    bf16* __restrict__ ko, bf16* __restrict__ vt2)
{
    int chunk = blockIdx.x, b = blockIdx.y;
    int tid = threadIdx.x, w = tid >> 6, l = tid & 63;
    int lr = l & 15, lc = (l >> 4) * 8;
    int rowb = chunk * 64 + w * 16;
    const float* xb = x + (size_t)b * NC * NE;

    __shared__ float sts[64];
    if (tid < 64) {
        float s = 0.f;
        #pragma unroll
        for (int p = 0; p < 16; ++p) s += sp[(size_t)(b * 16 + p) * 64 + tid];
        sts[tid] = 1.f / s;
    }

    bf16v8 bfr[4][2];
    float fbias[4];
    #pragma unroll
    for (int nt = 0; nt < 4; ++nt) {
        #pragma unroll
        for (int kt = 0; kt < 2; ++kt) {
            const float* p = fw + (nt*16 + lr) * 64 + kt*32 + lc;
            bf16v8 t;
            #pragma unroll
            for (int j = 0; j < 8; ++j) t[j] = (__bf16)p[j];
            bfr[nt][kt] = t;
        }
        fbias[nt] = fb[nt*16 + lr];
    }
    __syncthreads();

    float isA[8], isB[8];
    #pragma unroll
    for (int j = 0; j < 8; ++j) { isA[j] = sts[lc + j]; isB[j] = sts[32 + lc + j]; }

    const float* pa = xb + (size_t)(rowb + lr) * NE;
    float xa[8], xc[8];
    #pragma unroll
    for (int j = 0; j < 8; ++j) xa[j] = pa[lc + j];
    #pragma unroll
    for (int j = 0; j < 8; ++j) xc[j] = pa[32 + lc + j];

    bf16v8 a0, a1;
    #pragma unroll
    for (int j = 0; j < 8; ++j) a0[j] = (__bf16)xa[j];
    #pragma unroll
    for (int j = 0; j < 8; ++j) a1[j] = (__bf16)xc[j];

    // ---- k path from registers ----
    bf16v8 kv0, kv1;
    #pragma unroll
    for (int j = 0; j < 8; ++j) kv0[j] = (__bf16)gelu_exact(__expf(xa[j]) * isA[j]);
    #pragma unroll
    for (int j = 0; j < 8; ++j) kv1[j] = (__bf16)gelu_exact(__expf(xc[j]) * isB[j]);
    bf16* kp = ko + ((size_t)b * NC + rowb + lr) * NE + lc;
    *(bf16v8*)kp = kv0;
    *(bf16v8*)(kp + 32) = kv1;

    // ---- v MFMAs -> tiled store ----
    int c0 = rowb + (l >> 4) * 4;          // 4 consecutive k-rows, same tile
    int ktile = c0 >> 5, kc = c0 & 31;
    #pragma unroll
    for (int nt = 0; nt < 4; ++nt) {
        f32x4 acc = {fbias[nt], fbias[nt], fbias[nt], fbias[nt]};
        acc = MFMA16(a0, bfr[nt][0], acc);
        acc = MFMA16(a1, bfr[nt][1], acc);
        bf16v4 pk;
        #pragma unroll
        for (int r = 0; r < 4; ++r) pk[r] = (__bf16)gelu_exact(acc[r]);
        *(bf16v4*)&vt2[(((size_t)b * 24 + ktile) * 64 + nt*16 + lr) * 32 + kc] = pk;
    }
}

// ---------------------------------------------------------------------------
// softmax + P-redistribution for one 16-q tile (verified mapping, rounds 3-19):
// lane holds S[k-frag rows][q=lr]; returns PV A-frag P[q=lr][k chunk hi*8..+7].
// __expf on pre-scaled (0.125) scores — the FAST ocml path (r13 lesson).
// ---------------------------------------------------------------------------
__device__ __forceinline__ bf16v8 softmax_exch(f32x4 s0, f32x4 s1, float& rsum,
                                               int srcA, int srcB, int hq) {
    float p0 = __expf(s0[0]), p1 = __expf(s0[1]), p2 = __expf(s0[2]), p3 = __expf(s0[3]);
    float p4 = __expf(s1[0]), p5 = __expf(s1[1]), p6 = __expf(s1[2]), p7 = __expf(s1[3]);
    rsum += ((p0 + p1) + (p2 + p3)) + ((p4 + p5) + (p6 + p7));
    bf16v2 t0; t0[0] = (__bf16)p0; t0[1] = (__bf16)p1;
    bf16v2 t1; t1[0] = (__bf16)p2; t1[1] = (__bf16)p3;
    bf16v2 t2; t2[0] = (__bf16)p4; t2[1] = (__bf16)p5;
    bf16v2 t3; t3[0] = (__bf16)p6; t3[1] = (__bf16)p7;
    u32 w0 = __builtin_bit_cast(u32, t0), w1 = __builtin_bit_cast(u32, t1);
    u32 w2 = __builtin_bit_cast(u32, t2), w3 = __builtin_bit_cast(u32, t3);
    u32 c0A = (u32)__shfl((int)w0, srcA), c1A = (u32)__shfl((int)w1, srcA);
    u32 c2A = (u32)__shfl((int)w2, srcA), c3A = (u32)__shfl((int)w3, srcA);
    u32 c0B = (u32)__shfl((int)w0, srcB), c1B = (u32)__shfl((int)w1, srcB);
    u32 c2B = (u32)__shfl((int)w2, srcB), c3B = (u32)__shfl((int)w3, srcB);
    u32x4 pau = { hq ? c2A : c0A, hq ? c3A : c1A,
                  hq ? c2B : c0B, hq ? c3B : c1B };
    return __builtin_bit_cast(bf16v8, pau);
}

// ---------------------------------------------------------------------------
// Kernel 3: attention — 16x16 body, __expf softmax, tiled-V contiguous
// staging, 2-buf BK=64, setprio, verified swizzles (r14 configuration;
// measured invariant to occupancy/pipeline/tile variants rounds 10-18).
// Grid 768 = 8 XCD * 96; LDS 32 KB; 3 blocks/CU.
// ---------------------------------------------------------------------------
__global__ __launch_bounds__(256, 3) void k_attn(const bf16* __restrict__ qb,
                                                 const bf16* __restrict__ kb,
                                                 const bf16* __restrict__ vt2,
                                                 float* __restrict__ out) {
    __shared__ __align__(16) __bf16 ldsK[2][4096];   // [buf][2 sub][32 r][64 e]
    __shared__ __align__(16) __bf16 ldsV[2][4096];   // [buf][2 sub][64 e][32 k]

    int bid = blockIdx.x;
    int swz = (bid & 7) * 96 + (bid >> 3);      // bijective: 768 = 8*96
    int b = swz / 6, qt = swz - b * 6;
    int w = threadIdx.x >> 6, l = threadIdx.x & 63;
    int q0 = qt * 128 + w * 32;
    int lr = l & 15, hi = l >> 4;
    int hq = hi >> 1;
    int srcA = lr + ((hi & 1) << 5);
    int srcB = srcA + 16;

    // staging source addresses (inverse-swizzled; K rows, V tiled 4KB)
    int krow_ = w * 8 + (l >> 3);
    int kc16_ = (l & 7) ^ (l >> 3);
    const char* kgbase = (const char*)(kb + (size_t)b * NC * NE)
                       + krow_ * 128 + kc16_ * 16;
    int ve_   = w * 16 + (l >> 2);
    int vc16_ = (l & 3) ^ ((l >> 3) & 3);
    const char* vgbase = (const char*)vt2 + (size_t)b * 24 * 4096
                       + ve_ * 64 + vc16_ * 16;

    // swizzled ds_read element offsets (within a 2048-elem subtile)
    int krd0 = lr * 64 + ((hi ^ (lr & 7)) << 3);
    int krd1 = lr * 64 + (((4 + hi) ^ (lr & 7)) << 3);
    int vsel = (lr >> 1) & 3;
    int vrd  = lr * 32 + ((hi ^ vsel) << 3);

    const bf16* qp = qb + ((size_t)b * NC + q0 + lr) * NE + hi * 8;
    bf16v8 qf00 = *(const bf16v8*)qp;
    bf16v8 qf01 = *(const bf16v8*)(qp + 32);
    bf16v8 qf10 = *(const bf16v8*)(qp + 16 * NE);
    bf16v8 qf11 = *(const bf16v8*)(qp + 16 * NE + 32);

    f32x4 o00 = {0,0,0,0}, o01 = {0,0,0,0}, o02 = {0,0,0,0}, o03 = {0,0,0,0};
    f32x4 o10 = {0,0,0,0}, o11 = {0,0,0,0}, o12 = {0,0,0,0}, o13 = {0,0,0,0};
    float rsum0 = 0.f, rsum1 = 0.f;

    // prologue: stage k-tiles 0,1 into buf 0 (V tile stride 4096 B)
    gload_lds16(kgbase,        &ldsK[0][w * 512]);
    gload_lds16(kgbase + 4096, &ldsK[0][2048 + w * 512]);
    gload_lds16(vgbase,        &ldsV[0][w * 512]);
    gload_lds16(vgbase + 4096, &ldsV[0][2048 + w * 512]);
    __syncthreads();

    int cur = 0;
    for (int ph = 0; ph < 12; ++ph) {
        if (ph < 11) {   // stage k-tiles 2ph+2, 2ph+3 into the other buffer
            const char* kg = kgbase + (size_t)(2 * ph + 2) * 4096;
            gload_lds16(kg,        &ldsK[cur ^ 1][w * 512]);
            gload_lds16(kg + 4096, &ldsK[cur ^ 1][2048 + w * 512]);
            const char* vg = vgbase + (size_t)(2 * ph + 2) * 4096;
            gload_lds16(vg,        &ldsV[cur ^ 1][w * 512]);
            gload_lds16(vg + 4096, &ldsV[cur ^ 1][2048 + w * 512]);
        }

        #pragma unroll
        for (int sub = 0; sub < 2; ++sub) {
            const __bf16* Kc = &ldsK[cur][sub * 2048];
            const __bf16* Vc = &ldsV[cur][sub * 2048];
            bf16v8 ka0 = *(const bf16v8*)&Kc[krd0];
            bf16v8 ka1 = *(const bf16v8*)&Kc[krd1];
            bf16v8 ka2 = *(const bf16v8*)&Kc[krd0 + 1024];
            bf16v8 ka3 = *(const bf16v8*)&Kc[krd1 + 1024];
            bf16v8 v0  = *(const bf16v8*)&Vc[vrd];
            bf16v8 v1  = *(const bf16v8*)&Vc[vrd + 512];
            bf16v8 v2  = *(const bf16v8*)&Vc[vrd + 1024];
            bf16v8 v3  = *(const bf16v8*)&Vc[vrd + 1536];

            __builtin_amdgcn_s_setprio(1);
            f32x4 s00 = {0,0,0,0}, s01 = {0,0,0,0};
            s00 = MFMA16(ka0, qf00, s00);
            s00 = MFMA16(ka1, qf01, s00);
            s01 = MFMA16(ka2, qf00, s01);
            s01 = MFMA16(ka3, qf01, s01);
            f32x4 s10 = {0,0,0,0}, s11 = {0,0,0,0};
            s10 = MFMA16(ka0, qf10, s10);
            s10 = MFMA16(ka1, qf11, s10);
            s11 = MFMA16(ka2, qf10, s11);
            s11 = MFMA16(ka3, qf11, s11);
            __builtin_amdgcn_s_setprio(0);

            bf16v8 pa0 = softmax_exch(s00, s01, rsum0, srcA, srcB, hq);
            bf16v8 pa1 = softmax_exch(s10, s11, rsum1, srcA, srcB, hq);

            __builtin_amdgcn_s_setprio(1);
            o00 = MFMA16(pa0, v0, o00);
            o01 = MFMA16(pa0, v1, o01);
            o02 = MFMA16(pa0, v2, o02);
            o03 = MFMA16(pa0, v3, o03);
            o10 = MFMA16(pa1, v0, o10);
            o11 = MFMA16(pa1, v1, o11);
            o12 = MFMA16(pa1, v2, o12);
            o13 = MFMA16(pa1, v3, o13);
            __builtin_amdgcn_s_setprio(0);
        }

        __syncthreads();   // drains staging vmcnt; flips buffers safely
        cur ^= 1;
    }

    rsum0 += __shfl_xor(rsum0, 16);
    rsum0 += __shfl_xor(rsum0, 32);
    rsum1 += __shfl_xor(rsum1, 16);
    rsum1 += __shfl_xor(rsum1, 32);
    float inv0 = 1.f / rsum0, inv1 = 1.f / rsum1;

    int qrow0 = q0 + hi * 4;
    #pragma unroll
    for (int r = 0; r < 4; ++r) {
        float iq = __shfl(inv0, hi * 4 + r);
        float* op = out + ((size_t)b * NC + qrow0 + r) * NE + lr;
        op[0]  = o00[r] * iq;
        op[16] = o01[r] * iq;
        op[32] = o02[r] * iq;
        op[48] = o03[r] * iq;
    }
    int qrow1 = q0 + 16 + hi * 4;
    #pragma unroll
    for (int r = 0; r < 4; ++r) {
        float iq = __shfl(inv1, hi * 4 + r);
        float* op = out + ((size_t)b * NC + qrow1 + r) * NE + lr;
        op[0]  = o10[r] * iq;
        op[16] = o11[r] * iq;
        op[32] = o12[r] * iq;
        op[48] = o13[r] * iq;
    }
}

// ---------------------------------------------------------------------------
extern "C" void kernel_launch(void* const* d_in, const int* in_sizes, int n_in,
                              void* d_out, int out_size, void* d_ws, size_t ws_size,
                              hipStream_t stream) {
    (void)in_sizes; (void)n_in; (void)out_size; (void)ws_size;
    const float* x      = (const float*)d_in[0];
    const float* conv_w = (const float*)d_in[1];
    const float* conv_b = (const float*)d_in[2];
    const float* ln_g   = (const float*)d_in[3];
    const float* ln_b   = (const float*)d_in[4];
    const float* fi_w   = (const float*)d_in[5];
    const float* fi_b   = (const float*)d_in[6];
    // bi_w/bi_b unused: mask is constant along softmax axis -> exact no-op.

    bf16* qbuf = (bf16*)d_ws;
    bf16* kbuf = qbuf + (size_t)NB * NC * NE;
    bf16* vt2  = kbuf + (size_t)NB * NC * NE;             // tiled V
    float* stats = (float*)(vt2 + (size_t)NB * NC * NE);  // NB*16*64 f32
    float* out = (float*)d_out;

    k_conv<<<dim3(NB * 16), 256, 0, stream>>>(x, conv_w, conv_b, ln_g, ln_b,
                                              qbuf, stats);
    k_vk<<<dim3(12, NB), 256, 0, stream>>>(x, fi_w, fi_b, stats, kbuf, vt2);
    k_attn<<<dim3(768), 256, 0, stream>>>(qbuf, kbuf, vt2, out);
}